// Round 8
// baseline (1068.166 us; speedup 1.0000x reference)
//
#include <hip/hip_runtime.h>
#include <hip/hip_bf16.h>
#include <math.h>

#define N_NODES 50000
#define N_EDGES 800000
#define N_MOLS  2000
#define EPB     128   // edges per block in edge_mfma_kernel (divides N_EDGES)

static constexpr float BN_INV_F = 0.9999950000374997f; // 1/sqrt(1+1e-5)

enum { ACT_NONE = 0, ACT_LEAKY = 1, ACT_BN_DL = 2 };

typedef float f32x4 __attribute__((ext_vector_type(4)));
typedef short bf16x8 __attribute__((ext_vector_type(8)));

static __device__ __forceinline__ float b2f(short s) {
    unsigned u = ((unsigned)(unsigned short)s) << 16;
    return __builtin_bit_cast(float, u);
}
static __device__ __forceinline__ short f2bs(float v) {
    return __builtin_bit_cast(short, __float2bfloat16(v));
}

// ---------------- counting sort of edges by dst ----------------

__global__ void hist_kernel(const int* __restrict__ ei, int* __restrict__ cnt) {
    int e = blockIdx.x * 256 + threadIdx.x;
    if (e < N_EDGES) atomicAdd(&cnt[ei[N_EDGES + e]], 1);
}

__global__ __launch_bounds__(1024) void scan1_kernel(const int* __restrict__ cnt,
                                                     int* __restrict__ incl,
                                                     int* __restrict__ bsum) {
    __shared__ int sd[1024];
    int i = blockIdx.x * 1024 + threadIdx.x;
    int v = (i < N_NODES) ? cnt[i] : 0;
    sd[threadIdx.x] = v;
    __syncthreads();
    for (int off = 1; off < 1024; off <<= 1) {
        int t = (threadIdx.x >= off) ? sd[threadIdx.x - off] : 0;
        __syncthreads();
        sd[threadIdx.x] += t;
        __syncthreads();
    }
    incl[i] = sd[threadIdx.x];
    if (threadIdx.x == 1023) bsum[blockIdx.x] = sd[1023];
}

__global__ void scan2_kernel(const int* __restrict__ bsum, int* __restrict__ bex, int nblk) {
    if (threadIdx.x == 0) {
        int run = 0;
        for (int b = 0; b < nblk; ++b) { bex[b] = run; run += bsum[b]; }
    }
}

__global__ __launch_bounds__(1024) void scan3_kernel(const int* __restrict__ cnt,
                                                     const int* __restrict__ incl,
                                                     const int* __restrict__ bex,
                                                     int* __restrict__ cursor) {
    int i = blockIdx.x * 1024 + threadIdx.x;
    if (i < N_NODES) cursor[i] = bex[blockIdx.x] + incl[i] - cnt[i];
}

// scatter: emit src/dst per sorted position AND pre-gather ea (as bf16) into sorted order
__global__ void scatter_kernel(const int* __restrict__ ei, int* __restrict__ cursor,
                               const float* __restrict__ ea,
                               int* __restrict__ srcs, int* __restrict__ dsts,
                               __hip_bfloat16* __restrict__ eas) {
    int e = blockIdx.x * 256 + threadIdx.x;
    if (e < N_EDGES) {
        int d = ei[N_EDGES + e];
        int pos = atomicAdd(&cursor[d], 1);
        srcs[pos] = ei[e];
        dsts[pos] = d;
        const f32x4* s4 = (const f32x4*)(ea + (size_t)e * 16);
        f32x4 a0 = s4[0], a1 = s4[1], a2 = s4[2], a3 = s4[3];
        bf16x8 lo, hi;
#pragma unroll
        for (int j = 0; j < 4; ++j) {
            lo[j] = f2bs(a0[j]); lo[4 + j] = f2bs(a1[j]);
            hi[j] = f2bs(a2[j]); hi[4 + j] = f2bs(a3[j]);
        }
        bf16x8* d8 = (bf16x8*)(eas + (size_t)pos * 16);
        d8[0] = lo; d8[1] = hi;
    }
}

// ---------------- all weight converts/transposes in one launch ----------------
// Wt layouts: [DOUT][DIN] bf16 for node/cls weights; [D][16] bf16 for edge weights.

__global__ __launch_bounds__(256) void cvt_all_kernel(
        const float* __restrict__ c1W, const float* __restrict__ cW,
        const float* __restrict__ cls1W, const float* __restrict__ clsW,
        const float* __restrict__ c1eW, const float* __restrict__ ceW,
        __hip_bfloat16* __restrict__ wt1, __hip_bfloat16* __restrict__ wtc,
        __hip_bfloat16* __restrict__ wtcls1, __hip_bfloat16* __restrict__ wtcls,
        __hip_bfloat16* __restrict__ ewt1, __hip_bfloat16* __restrict__ ewtc) {
    int o = blockIdx.x * 256 + threadIdx.x;
    auto cvt = [](const float* s, __hip_bfloat16* d, int K, int Nc, int off) {
        int n = off / K, k = off - n * K;
        d[off] = __float2bfloat16(s[(size_t)k * Nc + n]);
    };
    if (o < 8192) cvt(c1W, wt1, 64, 128, o);
    else if (o < 73728)  { int s = o - 8192;   int i = s >> 14, off = s & 16383;
        cvt(cW + i * 16384, wtc + i * 16384, 128, 128, off); }
    else if (o < 237568) cvt(cls1W, wtcls1, 640, 256, o - 73728);
    else if (o < 368640) { int s = o - 237568; int i = s >> 16, off = s & 65535;
        cvt(clsW + i * 65536, wtcls + i * 65536, 256, 256, off); }
    else if (o < 369664) cvt(c1eW, ewt1, 16, 64, o - 368640);
    else if (o < 377856) { int s = o - 369664; int i = s >> 11, off = s & 2047;
        cvt(ceW + i * 2048, ewtc + i * 2048, 16, 128, off); }
}

// ---------------- edge kernel: MFMA e-linear + segmented aggregation ----------------

template<int D, bool F32IN>
__global__ __launch_bounds__(256) void edge_mfma_kernel(
        const void* __restrict__ hin_, int ld,
        const __hip_bfloat16* __restrict__ eas,   // [E][16] bf16, dst-sorted
        const int* __restrict__ srcs,
        const int* __restrict__ dsts,
        const __hip_bfloat16* __restrict__ eWt,   // [D][16] bf16
        const float* __restrict__ eb,             // [D]
        float* __restrict__ t32) {
    constexpr int SP = D + 4;          // LDS row stride (bf16 elems)
    constexpr int NCT = D / 16;        // col tiles
    constexpr int GROUPS = 256 / D;
    constexpr int EPG = EPB / GROUPS;
    __shared__ __hip_bfloat16 e_lds[EPB * SP];
    const int tid = threadIdx.x;
    const int wid = tid >> 6, lane = tid & 63;
    const int lrow = lane & 15;
    const int lkg = lane >> 4;         // 0..3
    const bool hiK = lkg >= 2;         // k 16..31 -> zero pad
    const int lko = (lkg & 1) * 8;     // offset within the 16 real k's
    const int p0 = blockIdx.x * EPB;

    // ---- phase A ----
    bf16x8 bfrag[NCT];
#pragma unroll
    for (int ct = 0; ct < NCT; ++ct) {
        bf16x8 bv = *reinterpret_cast<const bf16x8*>(&eWt[(ct * 16 + lrow) * 16 + lko]);
        if (hiK) bv = (bf16x8){0, 0, 0, 0, 0, 0, 0, 0};
        bfrag[ct] = bv;
    }
#pragma unroll
    for (int et = 0; et < 2; ++et) {
        const int erow = (wid * 2 + et) * 16;   // local edge tile base
        bf16x8 av = *reinterpret_cast<const bf16x8*>(
            &eas[(size_t)(p0 + erow + lrow) * 16 + lko]);
        if (hiK) av = (bf16x8){0, 0, 0, 0, 0, 0, 0, 0};
        const int r0 = erow + lkg * 4;
#pragma unroll
        for (int ct = 0; ct < NCT; ++ct) {
            f32x4 c = (f32x4){0.f, 0.f, 0.f, 0.f};
            c = __builtin_amdgcn_mfma_f32_16x16x32_bf16(av, bfrag[ct], c, 0, 0, 0);
            const int col = ct * 16 + lrow;
            const float bi = eb[col];
#pragma unroll
            for (int r = 0; r < 4; ++r)
                e_lds[(r0 + r) * SP + col] = __float2bfloat16(c[r] + bi);
        }
    }
    __syncthreads();

    // ---- phase B ----
    const float* hf = (const float*)hin_;
    const __hip_bfloat16* hb = (const __hip_bfloat16*)hin_;
    const int g = tid / D;
    const int f = tid - g * D;
    const int q0 = g * EPG;
    int cur = dsts[p0 + q0];
    float acc = 0.f;
    for (int q = q0; q < q0 + EPG; q += 8) {
        int s[8], d[8];
#pragma unroll
        for (int j = 0; j < 8; ++j) { s[j] = srcs[p0 + q + j]; d[j] = dsts[p0 + q + j]; }
        float h[8];
#pragma unroll
        for (int j = 0; j < 8; ++j)
            h[j] = F32IN ? hf[(size_t)s[j] * ld + f]
                         : __bfloat162float(hb[(size_t)s[j] * ld + f]);
        float e[8];
#pragma unroll
        for (int j = 0; j < 8; ++j)
            e[j] = __bfloat162float(e_lds[(q + j) * SP + f]);
#pragma unroll
        for (int j = 0; j < 8; ++j) {
            if (d[j] != cur) {             // group-uniform branch
                atomicAdd(&t32[(size_t)cur * D + f], acc);
                acc = 0.f; cur = d[j];
            }
            acc += fmaxf(h[j] + e[j], 0.f);
        }
    }
    atomicAdd(&t32[(size_t)cur * D + f], acc);
}

// ---------------- bf16 MFMA linear: C = act((t32 + hin) @ W + b) ----------------
// Latency-optimized: 4 waves (2 row x 2 col), each wave 16 rows x DOUT/2 cols.
// ALL A-fragments for the full K extent are loaded/built up front (statically
// indexed registers, fully unrolled) -> one latency exposure per tile.
// B streams per-ks from L2 inside a fully unrolled loop.

template<int DIN, int DOUT, int ACT, int SELF>
__global__ __launch_bounds__(256) void mfma_lin_kernel(
        const void* __restrict__ A_, int lda,
        const float* __restrict__ t32,
        const __hip_bfloat16* __restrict__ Wt,  // [DOUT][DIN]
        const float* __restrict__ bias,
        const float* __restrict__ gamma,
        const float* __restrict__ beta,
        __hip_bfloat16* __restrict__ C, int ldc) {
    constexpr int NT = DOUT / 32;   // 16-col tiles per wave (wc covers DOUT/2)
    constexpr int NKS = DIN / 32;
    const int wid = threadIdx.x >> 6, lane = threadIdx.x & 63;
    const int wr = wid >> 1, wc = wid & 1;
    const int row_base = blockIdx.x * 32 + wr * 16;
    const int col_base = wc * NT * 16;
    const int lrow = lane & 15;
    const int lk = (lane >> 4) * 8;

    int arow = row_base + lrow;
    arow = arow < N_NODES ? arow : N_NODES - 1;

    // ---- build all A fragments up front ----
    bf16x8 a[NKS];
    if constexpr (SELF == 0) {
        const __hip_bfloat16* Ab = (const __hip_bfloat16*)A_;
#pragma unroll
        for (int ks = 0; ks < NKS; ++ks)
            a[ks] = *reinterpret_cast<const bf16x8*>(&Ab[(size_t)arow * lda + ks * 32 + lk]);
    } else if constexpr (SELF == 1) {
        const float* Af = (const float*)A_;
        f32x4 t0[NKS], t1[NKS], h0[NKS], h1[NKS];
#pragma unroll
        for (int ks = 0; ks < NKS; ++ks) {
            const int kc = ks * 32 + lk;
            t0[ks] = *(const f32x4*)&t32[(size_t)arow * DIN + kc];
            t1[ks] = *(const f32x4*)&t32[(size_t)arow * DIN + kc + 4];
            h0[ks] = *(const f32x4*)&Af[(size_t)arow * lda + kc];
            h1[ks] = *(const f32x4*)&Af[(size_t)arow * lda + kc + 4];
        }
#pragma unroll
        for (int ks = 0; ks < NKS; ++ks)
#pragma unroll
            for (int j = 0; j < 4; ++j) {
                a[ks][j]     = f2bs(t0[ks][j] + h0[ks][j]);
                a[ks][4 + j] = f2bs(t1[ks][j] + h1[ks][j]);
            }
    } else {
        const __hip_bfloat16* Ab = (const __hip_bfloat16*)A_;
        f32x4 t0[NKS], t1[NKS];
        bf16x8 hv[NKS];
#pragma unroll
        for (int ks = 0; ks < NKS; ++ks) {
            const int kc = ks * 32 + lk;
            t0[ks] = *(const f32x4*)&t32[(size_t)arow * DIN + kc];
            t1[ks] = *(const f32x4*)&t32[(size_t)arow * DIN + kc + 4];
            hv[ks] = *reinterpret_cast<const bf16x8*>(&Ab[(size_t)arow * lda + kc]);
        }
#pragma unroll
        for (int ks = 0; ks < NKS; ++ks)
#pragma unroll
            for (int j = 0; j < 4; ++j) {
                a[ks][j]     = f2bs(t0[ks][j] + b2f(hv[ks][j]));
                a[ks][4 + j] = f2bs(t1[ks][j] + b2f(hv[ks][4 + j]));
            }
    }

    // ---- K loop: stream B, accumulate ----
    f32x4 acc[NT];
#pragma unroll
    for (int nt = 0; nt < NT; ++nt) acc[nt] = (f32x4){0.f, 0.f, 0.f, 0.f};
#pragma unroll
    for (int ks = 0; ks < NKS; ++ks) {
        const int kc = ks * 32 + lk;
#pragma unroll
        for (int nt = 0; nt < NT; ++nt) {
            bf16x8 b = *reinterpret_cast<const bf16x8*>(
                &Wt[(size_t)(col_base + nt * 16 + lrow) * DIN + kc]);
            acc[nt] = __builtin_amdgcn_mfma_f32_16x16x32_bf16(a[ks], b, acc[nt], 0, 0, 0);
        }
    }

    // ---- epilogue ----
    const int r0 = row_base + (lane >> 4) * 4;
#pragma unroll
    for (int nt = 0; nt < NT; ++nt) {
        int c = col_base + nt * 16 + lrow;
        float bi = bias[c];
        float ga = (ACT == ACT_BN_DL) ? gamma[c] : 0.f;
        float be = (ACT == ACT_BN_DL) ? beta[c] : 0.f;
#pragma unroll
        for (int r = 0; r < 4; ++r) {
            int row = r0 + r;
            if (row < N_NODES) {
                float v = acc[nt][r] + bi;
                if (ACT == ACT_BN_DL) {
                    v = ga * (v * BN_INV_F) + be;
                    v = v > 0.f ? v : 1e-4f * v;   // leaky(leaky(v))
                } else if (ACT == ACT_LEAKY) {
                    v = v > 0.f ? v : 0.01f * v;
                }
                C[(size_t)row * ldc + c] = __float2bfloat16(v);
            }
        }
    }
}

// ---------------- pooling ----------------

__global__ void pool_add_kernel(const __hip_bfloat16* __restrict__ concat,
                                const int* __restrict__ batch,
                                float* __restrict__ pool) {
    int idx = blockIdx.x * 256 + threadIdx.x;
    if (idx >= N_NODES * 128) return;
    int n = idx >> 7, f = idx & 127;
    atomicAdd(&pool[batch[n] * 128 + f],
              __bfloat162float(concat[(size_t)n * 640 + 384 + f]));
}

__global__ void pool_gather_kernel(__hip_bfloat16* __restrict__ concat,
                                   const int* __restrict__ batch,
                                   const float* __restrict__ pool) {
    int idx = blockIdx.x * 256 + threadIdx.x;
    if (idx >= N_NODES * 128) return;
    int n = idx >> 7, f = idx & 127;
    concat[(size_t)n * 640 + 512 + f] = __float2bfloat16(pool[batch[n] * 128 + f]);
}

// ---------------- final 256 -> 1 + sigmoid ----------------

__global__ __launch_bounds__(256) void final_kernel(const __hip_bfloat16* __restrict__ A,
                                                    const float* __restrict__ fW,
                                                    const float* __restrict__ fb,
                                                    float* __restrict__ out) {
    int wave = threadIdx.x >> 6;
    int lane = threadIdx.x & 63;
    int row = blockIdx.x * 4 + wave;
    const __hip_bfloat16* ar = A + (size_t)row * 256;
    float p = 0.f;
#pragma unroll
    for (int i = 0; i < 4; ++i) {
        int k = lane + i * 64;
        p += __bfloat162float(ar[k]) * fW[k];
    }
#pragma unroll
    for (int off = 32; off >= 1; off >>= 1) p += __shfl_xor(p, off, 64);
    if (lane == 0) out[row] = 1.f / (1.f + expf(-(p + fb[0])));
}

// ---------------- launch ----------------

extern "C" void kernel_launch(void* const* d_in, const int* in_sizes, int n_in,
                              void* d_out, int out_size, void* d_ws, size_t ws_size,
                              hipStream_t stream) {
    const float* x     = (const float*)d_in[0];
    const int*   ei    = (const int*)d_in[1];
    const float* ea    = (const float*)d_in[2];
    const int*   batch = (const int*)d_in[3];
    const float* c1W   = (const float*)d_in[4];
    const float* c1b   = (const float*)d_in[5];
    const float* c1g   = (const float*)d_in[6];
    const float* c1be  = (const float*)d_in[7];
    const float* c1eW  = (const float*)d_in[8];
    const float* c1eb  = (const float*)d_in[9];
    const float* cW    = (const float*)d_in[10];
    const float* cb    = (const float*)d_in[11];
    const float* cg    = (const float*)d_in[12];
    const float* cbe   = (const float*)d_in[13];
    const float* ceW   = (const float*)d_in[14];
    const float* ceb   = (const float*)d_in[15];
    const float* cls1W = (const float*)d_in[16];
    const float* cls1b = (const float*)d_in[17];
    const float* clsW  = (const float*)d_in[18];
    const float* clsb  = (const float*)d_in[19];
    const float* fW    = (const float*)d_in[20];
    const float* fb    = (const float*)d_in[21];
    float* out = (float*)d_out;

    char* ws = (char*)d_ws;
    size_t off = 0;
    auto alloc = [&](size_t bytes) {
        void* p = ws + off;
        off += (bytes + 255) & ~(size_t)255;
        return p;
    };
    const int NBLK = (N_NODES + 1023) / 1024;  // 49
    int*   srcs   = (int*)alloc((size_t)N_EDGES * 4);
    int*   dsts   = (int*)alloc((size_t)N_EDGES * 4);
    int*   cursor = (int*)alloc((size_t)N_NODES * 4);
    int*   cnt    = (int*)alloc((size_t)N_NODES * 4);
    int*   incl   = (int*)alloc((size_t)NBLK * 1024 * 4);
    int*   bsum   = (int*)alloc((size_t)NBLK * 4);
    int*   bex    = (int*)alloc((size_t)NBLK * 4);
    __hip_bfloat16* eas = (__hip_bfloat16*)alloc((size_t)N_EDGES * 16 * 2);  // 25.6 MB
    float* t32    = (float*)alloc((size_t)N_NODES * 128 * 4);                // 25.6 MB
    __hip_bfloat16* h1     = (__hip_bfloat16*)alloc((size_t)N_NODES * 128 * 2);
    float*          pool   = (float*)alloc((size_t)N_MOLS * 128 * 4);
    __hip_bfloat16* concat = (__hip_bfloat16*)alloc((size_t)N_NODES * 640 * 2); // 64 MB
    __hip_bfloat16* clsA   = (__hip_bfloat16*)alloc((size_t)N_NODES * 256 * 2);
    __hip_bfloat16* wt1    = (__hip_bfloat16*)alloc((size_t)128 * 64 * 2);
    __hip_bfloat16* wtc    = (__hip_bfloat16*)alloc((size_t)4 * 128 * 128 * 2);
    __hip_bfloat16* wtcls1 = (__hip_bfloat16*)alloc((size_t)256 * 640 * 2);
    __hip_bfloat16* wtcls  = (__hip_bfloat16*)alloc((size_t)2 * 256 * 256 * 2);
    __hip_bfloat16* ewt1   = (__hip_bfloat16*)alloc((size_t)64 * 16 * 2);
    __hip_bfloat16* ewtc   = (__hip_bfloat16*)alloc((size_t)4 * 128 * 16 * 2);
    __hip_bfloat16* clsB   = concat;  // overlay: concat dead after cls1

    hipMemsetAsync(cnt, 0, (size_t)N_NODES * 4, stream);
    hipMemsetAsync(pool, 0, (size_t)N_MOLS * 128 * 4, stream);

    // ---- edge sort by dst (emits srcs/dsts/eas-bf16) ----
    hist_kernel<<<(N_EDGES + 255) / 256, 256, 0, stream>>>(ei, cnt);
    scan1_kernel<<<NBLK, 1024, 0, stream>>>(cnt, incl, bsum);
    scan2_kernel<<<1, 64, 0, stream>>>(bsum, bex, NBLK);
    scan3_kernel<<<NBLK, 1024, 0, stream>>>(cnt, incl, bex, cursor);
    scatter_kernel<<<(N_EDGES + 255) / 256, 256, 0, stream>>>(ei, cursor, ea, srcs, dsts, eas);

    // ---- all weight converts in one launch ----
    cvt_all_kernel<<<(377856 + 255) / 256, 256, 0, stream>>>(
        c1W, cW, cls1W, clsW, c1eW, ceW, wt1, wtc, wtcls1, wtcls, ewt1, ewtc);

    const int NEB = N_EDGES / EPB;             // 6250
    const int GRID_LIN = (N_NODES + 31) / 32;  // 1563

    // ---- conv1: x [N,64] f32 -> h1 [N,128] ----
    hipMemsetAsync(t32, 0, (size_t)N_NODES * 64 * 4, stream);
    edge_mfma_kernel<64, true><<<NEB, 256, 0, stream>>>(
        x, 64, eas, srcs, dsts, ewt1, c1eb, t32);
    mfma_lin_kernel<64, 128, ACT_BN_DL, 1><<<GRID_LIN, 256, 0, stream>>>(
        x, 64, t32, wt1, c1b, c1g, c1be, h1, 128);

    // ---- conv layers 0..3 -> concat slices ----
    for (int i = 0; i < 4; ++i) {
        const void* hin = (i == 0) ? (const void*)h1 : (const void*)(concat + (size_t)(i - 1) * 128);
        int ld = (i == 0) ? 128 : 640;
        hipMemsetAsync(t32, 0, (size_t)N_NODES * 128 * 4, stream);
        edge_mfma_kernel<128, false><<<NEB, 256, 0, stream>>>(
            hin, ld, eas, srcs, dsts, ewtc + (size_t)i * 2048, ceb + (size_t)i * 128, t32);
        mfma_lin_kernel<128, 128, ACT_BN_DL, 2><<<GRID_LIN, 256, 0, stream>>>(
            hin, ld, t32, wtc + (size_t)i * 16384, cb + i * 128,
            cg + i * 128, cbe + i * 128, concat + (size_t)i * 128, 640);
    }

    // ---- global add pool (cols 384..511) -> cols 512..639 ----
    pool_add_kernel<<<(N_NODES * 128 + 255) / 256, 256, 0, stream>>>(concat, batch, pool);
    pool_gather_kernel<<<(N_NODES * 128 + 255) / 256, 256, 0, stream>>>(concat, batch, pool);

    // ---- classifier ----
    mfma_lin_kernel<640, 256, ACT_NONE, 0><<<GRID_LIN, 256, 0, stream>>>(
        concat, 640, nullptr, wtcls1, cls1b, nullptr, nullptr, clsA, 256);
    mfma_lin_kernel<256, 256, ACT_LEAKY, 0><<<GRID_LIN, 256, 0, stream>>>(
        clsA, 256, nullptr, wtcls, clsb, nullptr, nullptr, clsB, 256);
    mfma_lin_kernel<256, 256, ACT_LEAKY, 0><<<GRID_LIN, 256, 0, stream>>>(
        clsB, 256, nullptr, wtcls + 256 * 256, clsb + 256, nullptr, nullptr, clsA, 256);
    final_kernel<<<N_NODES / 4, 256, 0, stream>>>(clsA, fW, fb, out);
}

// Round 13
// 855.398 us; speedup vs baseline: 1.2487x; 1.2487x over previous
//
#include <hip/hip_runtime.h>
#include <hip/hip_bf16.h>
#include <math.h>

#define N_NODES 50000
#define N_EDGES 800000
#define N_MOLS  2000
#define EPB     128   // edges per block in edge_mfma_kernel (divides N_EDGES)

static constexpr float BN_INV_F = 0.9999950000374997f; // 1/sqrt(1+1e-5)

enum { ACT_NONE = 0, ACT_LEAKY = 1, ACT_BN_DL = 2 };

typedef float f32x4 __attribute__((ext_vector_type(4)));
typedef short bf16x8 __attribute__((ext_vector_type(8)));

static __device__ __forceinline__ float b2f(short s) {
    unsigned u = ((unsigned)(unsigned short)s) << 16;
    return __builtin_bit_cast(float, u);
}
static __device__ __forceinline__ short f2bs(float v) {
    return __builtin_bit_cast(short, __float2bfloat16(v));
}

// ---------------- counting sort of edges by dst ----------------

__global__ void hist_kernel(const int* __restrict__ ei, int* __restrict__ cnt) {
    int e = blockIdx.x * 256 + threadIdx.x;
    if (e < N_EDGES) atomicAdd(&cnt[ei[N_EDGES + e]], 1);
}

__global__ __launch_bounds__(1024) void scan1_kernel(const int* __restrict__ cnt,
                                                     int* __restrict__ incl,
                                                     int* __restrict__ bsum) {
    __shared__ int sd[1024];
    int i = blockIdx.x * 1024 + threadIdx.x;
    int v = (i < N_NODES) ? cnt[i] : 0;
    sd[threadIdx.x] = v;
    __syncthreads();
    for (int off = 1; off < 1024; off <<= 1) {
        int t = (threadIdx.x >= off) ? sd[threadIdx.x - off] : 0;
        __syncthreads();
        sd[threadIdx.x] += t;
        __syncthreads();
    }
    incl[i] = sd[threadIdx.x];
    if (threadIdx.x == 1023) bsum[blockIdx.x] = sd[1023];
}

__global__ void scan2_kernel(const int* __restrict__ bsum, int* __restrict__ bex, int nblk) {
    if (threadIdx.x == 0) {
        int run = 0;
        for (int b = 0; b < nblk; ++b) { bex[b] = run; run += bsum[b]; }
    }
}

__global__ __launch_bounds__(1024) void scan3_kernel(const int* __restrict__ cnt,
                                                     const int* __restrict__ incl,
                                                     const int* __restrict__ bex,
                                                     int* __restrict__ cursor) {
    int i = blockIdx.x * 1024 + threadIdx.x;
    if (i < N_NODES) cursor[i] = bex[blockIdx.x] + incl[i] - cnt[i];
}

// scatter: emit src/dst per sorted position AND pre-gather ea (as bf16) into sorted order
__global__ void scatter_kernel(const int* __restrict__ ei, int* __restrict__ cursor,
                               const float* __restrict__ ea,
                               int* __restrict__ srcs, int* __restrict__ dsts,
                               __hip_bfloat16* __restrict__ eas) {
    int e = blockIdx.x * 256 + threadIdx.x;
    if (e < N_EDGES) {
        int d = ei[N_EDGES + e];
        int pos = atomicAdd(&cursor[d], 1);
        srcs[pos] = ei[e];
        dsts[pos] = d;
        const f32x4* s4 = (const f32x4*)(ea + (size_t)e * 16);
        f32x4 a0 = s4[0], a1 = s4[1], a2 = s4[2], a3 = s4[3];
        bf16x8 lo, hi;
#pragma unroll
        for (int j = 0; j < 4; ++j) {
            lo[j] = f2bs(a0[j]); lo[4 + j] = f2bs(a1[j]);
            hi[j] = f2bs(a2[j]); hi[4 + j] = f2bs(a3[j]);
        }
        bf16x8* d8 = (bf16x8*)(eas + (size_t)pos * 16);
        d8[0] = lo; d8[1] = hi;
    }
}

// ---------------- all weight converts/transposes in one launch ----------------
// Wt layouts: [DOUT][DIN] bf16 for node/cls weights; [D][16] bf16 for edge weights.

__global__ __launch_bounds__(256) void cvt_all_kernel(
        const float* __restrict__ c1W, const float* __restrict__ cW,
        const float* __restrict__ cls1W, const float* __restrict__ clsW,
        const float* __restrict__ c1eW, const float* __restrict__ ceW,
        __hip_bfloat16* __restrict__ wt1, __hip_bfloat16* __restrict__ wtc,
        __hip_bfloat16* __restrict__ wtcls1, __hip_bfloat16* __restrict__ wtcls,
        __hip_bfloat16* __restrict__ ewt1, __hip_bfloat16* __restrict__ ewtc) {
    int o = blockIdx.x * 256 + threadIdx.x;
    auto cvt = [](const float* s, __hip_bfloat16* d, int K, int Nc, int off) {
        int n = off / K, k = off - n * K;
        d[off] = __float2bfloat16(s[(size_t)k * Nc + n]);
    };
    if (o < 8192) cvt(c1W, wt1, 64, 128, o);
    else if (o < 73728)  { int s = o - 8192;   int i = s >> 14, off = s & 16383;
        cvt(cW + i * 16384, wtc + i * 16384, 128, 128, off); }
    else if (o < 237568) cvt(cls1W, wtcls1, 640, 256, o - 73728);
    else if (o < 368640) { int s = o - 237568; int i = s >> 16, off = s & 65535;
        cvt(clsW + i * 65536, wtcls + i * 65536, 256, 256, off); }
    else if (o < 369664) cvt(c1eW, ewt1, 16, 64, o - 368640);
    else if (o < 377856) { int s = o - 369664; int i = s >> 11, off = s & 2047;
        cvt(ceW + i * 2048, ewtc + i * 2048, 16, 128, off); }
}

// ---------------- edge kernel: MFMA e-linear + segmented aggregation ----------------

template<int D, bool F32IN>
__global__ __launch_bounds__(256) void edge_mfma_kernel(
        const void* __restrict__ hin_, int ld,
        const __hip_bfloat16* __restrict__ eas,   // [E][16] bf16, dst-sorted
        const int* __restrict__ srcs,
        const int* __restrict__ dsts,
        const __hip_bfloat16* __restrict__ eWt,   // [D][16] bf16
        const float* __restrict__ eb,             // [D]
        float* __restrict__ t32) {
    constexpr int SP = D + 4;          // LDS row stride (bf16 elems)
    constexpr int NCT = D / 16;        // col tiles
    constexpr int GROUPS = 256 / D;
    constexpr int EPG = EPB / GROUPS;
    __shared__ __hip_bfloat16 e_lds[EPB * SP];
    const int tid = threadIdx.x;
    const int wid = tid >> 6, lane = tid & 63;
    const int lrow = lane & 15;
    const int lkg = lane >> 4;         // 0..3
    const bool hiK = lkg >= 2;         // k 16..31 -> zero pad
    const int lko = (lkg & 1) * 8;     // offset within the 16 real k's
    const int p0 = blockIdx.x * EPB;

    // ---- phase A ----
    bf16x8 bfrag[NCT];
#pragma unroll
    for (int ct = 0; ct < NCT; ++ct) {
        bf16x8 bv = *reinterpret_cast<const bf16x8*>(&eWt[(ct * 16 + lrow) * 16 + lko]);
        if (hiK) bv = (bf16x8){0, 0, 0, 0, 0, 0, 0, 0};
        bfrag[ct] = bv;
    }
#pragma unroll
    for (int et = 0; et < 2; ++et) {
        const int erow = (wid * 2 + et) * 16;   // local edge tile base
        bf16x8 av = *reinterpret_cast<const bf16x8*>(
            &eas[(size_t)(p0 + erow + lrow) * 16 + lko]);
        if (hiK) av = (bf16x8){0, 0, 0, 0, 0, 0, 0, 0};
        const int r0 = erow + lkg * 4;
#pragma unroll
        for (int ct = 0; ct < NCT; ++ct) {
            f32x4 c = (f32x4){0.f, 0.f, 0.f, 0.f};
            c = __builtin_amdgcn_mfma_f32_16x16x32_bf16(av, bfrag[ct], c, 0, 0, 0);
            const int col = ct * 16 + lrow;
            const float bi = eb[col];
#pragma unroll
            for (int r = 0; r < 4; ++r)
                e_lds[(r0 + r) * SP + col] = __float2bfloat16(c[r] + bi);
        }
    }
    __syncthreads();

    // ---- phase B ----
    const float* hf = (const float*)hin_;
    const __hip_bfloat16* hb = (const __hip_bfloat16*)hin_;
    const int g = tid / D;
    const int f = tid - g * D;
    const int q0 = g * EPG;
    int cur = dsts[p0 + q0];
    float acc = 0.f;
    for (int q = q0; q < q0 + EPG; q += 8) {
        int s[8], d[8];
#pragma unroll
        for (int j = 0; j < 8; ++j) { s[j] = srcs[p0 + q + j]; d[j] = dsts[p0 + q + j]; }
        float h[8];
#pragma unroll
        for (int j = 0; j < 8; ++j)
            h[j] = F32IN ? hf[(size_t)s[j] * ld + f]
                         : __bfloat162float(hb[(size_t)s[j] * ld + f]);
        float e[8];
#pragma unroll
        for (int j = 0; j < 8; ++j)
            e[j] = __bfloat162float(e_lds[(q + j) * SP + f]);
#pragma unroll
        for (int j = 0; j < 8; ++j) {
            if (d[j] != cur) {             // group-uniform branch
                atomicAdd(&t32[(size_t)cur * D + f], acc);
                acc = 0.f; cur = d[j];
            }
            acc += fmaxf(h[j] + e[j], 0.f);
        }
    }
    atomicAdd(&t32[(size_t)cur * D + f], acc);
}

// ---------------- bf16 MFMA linear: C = act((t32 + hin) @ W + b) ----------------
// v3: LDS-staged weights. Block = 4 waves = 64 rows x 64 cols; grid(row_tiles, DOUT/64).
// Per K-chunk (KC<=128): issue A-frag global loads (latency hides under staging),
// cooperatively stage Wt[64 x KC] into LDS (XOR-swizzled: chunk ^= row&7), barrier,
// K-loop reads B via ds_read_b128. One L2 exposure per chunk per BLOCK, not 16/wave.
// SELF: 0 = plain bf16 A; 1 = t32 + f32 hin; 2 = t32 + bf16 hin (SELF!=0 => single chunk).

template<int DIN, int DOUT, int ACT, int SELF>
__global__ __launch_bounds__(256, 4) void mfma_lin_kernel(
        const void* __restrict__ A_, int lda,
        const float* __restrict__ t32,
        const __hip_bfloat16* __restrict__ Wt,  // [DOUT][DIN]
        const float* __restrict__ bias,
        const float* __restrict__ gamma,
        const float* __restrict__ beta,
        __hip_bfloat16* __restrict__ C, int ldc) {
    constexpr int KC   = (DIN < 128) ? DIN : 128;  // K chunk
    constexpr int NCH  = DIN / KC;                 // chunks
    constexpr int NKSC = KC / 32;                  // k-steps per chunk
    constexpr int CPR  = KC / 8;                   // 16B chunks per LDS row
    constexpr int TC   = (64 * CPR) / 256;         // chunks staged per thread
    static_assert(SELF == 0 || NCH == 1, "SELF modes need single chunk");
    __shared__ __align__(16) short Bs[64 * KC];

    const int tid = threadIdx.x;
    const int wid = tid >> 6, lane = tid & 63;
    const int lrow = lane & 15;
    const int g = lane >> 4;
    const int lk = g * 8;
    const int row_base = blockIdx.x * 64 + wid * 16;
    const int col0 = blockIdx.y * 64;
    int arow = row_base + lrow;
    arow = arow < N_NODES ? arow : N_NODES - 1;

    // staging map: 4 threads per LDS row, TC consecutive 16B chunks each
    const int srow = tid >> 2;
    const int sc0 = (tid & 3) * TC;
    char* BsB = (char*)Bs;

    f32x4 acc[4];
#pragma unroll
    for (int nt = 0; nt < 4; ++nt) acc[nt] = (f32x4){0.f, 0.f, 0.f, 0.f};

    for (int ch = 0; ch < NCH; ++ch) {
        const int kc0 = ch * KC;

        // ---- issue A loads for this chunk (latency hides under staging) ----
        bf16x8 a[NKSC];
        f32x4 t0[NKSC], t1[NKSC];
        bf16x8 hv[NKSC];
        f32x4 h0[NKSC], h1[NKSC];
        if constexpr (SELF == 0) {
            const __hip_bfloat16* Ab = (const __hip_bfloat16*)A_;
#pragma unroll
            for (int ks = 0; ks < NKSC; ++ks)
                a[ks] = *reinterpret_cast<const bf16x8*>(
                    &Ab[(size_t)arow * lda + kc0 + ks * 32 + lk]);
        } else if constexpr (SELF == 1) {
            const float* Af = (const float*)A_;
#pragma unroll
            for (int ks = 0; ks < NKSC; ++ks) {
                const int kc = ks * 32 + lk;
                t0[ks] = *(const f32x4*)&t32[(size_t)arow * DIN + kc];
                t1[ks] = *(const f32x4*)&t32[(size_t)arow * DIN + kc + 4];
                h0[ks] = *(const f32x4*)&Af[(size_t)arow * lda + kc];
                h1[ks] = *(const f32x4*)&Af[(size_t)arow * lda + kc + 4];
            }
        } else {
            const __hip_bfloat16* Ab = (const __hip_bfloat16*)A_;
#pragma unroll
            for (int ks = 0; ks < NKSC; ++ks) {
                const int kc = ks * 32 + lk;
                t0[ks] = *(const f32x4*)&t32[(size_t)arow * DIN + kc];
                t1[ks] = *(const f32x4*)&t32[(size_t)arow * DIN + kc + 4];
                hv[ks] = *reinterpret_cast<const bf16x8*>(&Ab[(size_t)arow * lda + kc]);
            }
        }

        // ---- stage B chunk into LDS (swizzled) ----
        bf16x8 breg[TC];
#pragma unroll
        for (int j = 0; j < TC; ++j)
            breg[j] = *reinterpret_cast<const bf16x8*>(
                &Wt[(size_t)(col0 + srow) * DIN + kc0 + (sc0 + j) * 8]);
#pragma unroll
        for (int j = 0; j < TC; ++j) {
            const int c = sc0 + j;
            *(bf16x8*)(BsB + srow * (KC * 2) + ((c ^ (srow & 7)) * 16)) = breg[j];
        }
        __syncthreads();

        // ---- finish A build ----
        if constexpr (SELF == 1) {
#pragma unroll
            for (int ks = 0; ks < NKSC; ++ks)
#pragma unroll
                for (int j = 0; j < 4; ++j) {
                    a[ks][j]     = f2bs(t0[ks][j] + h0[ks][j]);
                    a[ks][4 + j] = f2bs(t1[ks][j] + h1[ks][j]);
                }
        } else if constexpr (SELF == 2) {
#pragma unroll
            for (int ks = 0; ks < NKSC; ++ks)
#pragma unroll
                for (int j = 0; j < 4; ++j) {
                    a[ks][j]     = f2bs(t0[ks][j] + b2f(hv[ks][j]));
                    a[ks][4 + j] = f2bs(t1[ks][j] + b2f(hv[ks][4 + j]));
                }
        }

        // ---- K loop: B from LDS ----
#pragma unroll
        for (int ks = 0; ks < NKSC; ++ks) {
#pragma unroll
            for (int nt = 0; nt < 4; ++nt) {
                const int brow = nt * 16 + lrow;
                const int c = ks * 4 + g;
                bf16x8 b = *(const bf16x8*)(
                    BsB + brow * (KC * 2) + ((c ^ (brow & 7)) * 16));
                acc[nt] = __builtin_amdgcn_mfma_f32_16x16x32_bf16(a[ks], b, acc[nt], 0, 0, 0);
            }
        }
        if (ch + 1 < NCH) __syncthreads();
    }

    // ---- epilogue ----
    const int r0 = row_base + g * 4;
#pragma unroll
    for (int nt = 0; nt < 4; ++nt) {
        int c = col0 + nt * 16 + lrow;
        float bi = bias[c];
        float ga = (ACT == ACT_BN_DL) ? gamma[c] : 0.f;
        float be = (ACT == ACT_BN_DL) ? beta[c] : 0.f;
#pragma unroll
        for (int r = 0; r < 4; ++r) {
            int row = r0 + r;
            if (row < N_NODES) {
                float v = acc[nt][r] + bi;
                if (ACT == ACT_BN_DL) {
                    v = ga * (v * BN_INV_F) + be;
                    v = v > 0.f ? v : 1e-4f * v;   // leaky(leaky(v))
                } else if (ACT == ACT_LEAKY) {
                    v = v > 0.f ? v : 0.01f * v;
                }
                C[(size_t)row * ldc + c] = __float2bfloat16(v);
            }
        }
    }
}

// ---------------- pooling ----------------

__global__ void pool_add_kernel(const __hip_bfloat16* __restrict__ concat,
                                const int* __restrict__ batch,
                                float* __restrict__ pool) {
    int idx = blockIdx.x * 256 + threadIdx.x;
    if (idx >= N_NODES * 128) return;
    int n = idx >> 7, f = idx & 127;
    atomicAdd(&pool[batch[n] * 128 + f],
              __bfloat162float(concat[(size_t)n * 640 + 384 + f]));
}

__global__ void pool_gather_kernel(__hip_bfloat16* __restrict__ concat,
                                   const int* __restrict__ batch,
                                   const float* __restrict__ pool) {
    int idx = blockIdx.x * 256 + threadIdx.x;
    if (idx >= N_NODES * 128) return;
    int n = idx >> 7, f = idx & 127;
    concat[(size_t)n * 640 + 512 + f] = __float2bfloat16(pool[batch[n] * 128 + f]);
}

// ---------------- final 256 -> 1 + sigmoid ----------------

__global__ __launch_bounds__(256) void final_kernel(const __hip_bfloat16* __restrict__ A,
                                                    const float* __restrict__ fW,
                                                    const float* __restrict__ fb,
                                                    float* __restrict__ out) {
    int wave = threadIdx.x >> 6;
    int lane = threadIdx.x & 63;
    int row = blockIdx.x * 4 + wave;
    const __hip_bfloat16* ar = A + (size_t)row * 256;
    float p = 0.f;
#pragma unroll
    for (int i = 0; i < 4; ++i) {
        int k = lane + i * 64;
        p += __bfloat162float(ar[k]) * fW[k];
    }
#pragma unroll
    for (int off = 32; off >= 1; off >>= 1) p += __shfl_xor(p, off, 64);
    if (lane == 0) out[row] = 1.f / (1.f + expf(-(p + fb[0])));
}

// ---------------- launch ----------------

extern "C" void kernel_launch(void* const* d_in, const int* in_sizes, int n_in,
                              void* d_out, int out_size, void* d_ws, size_t ws_size,
                              hipStream_t stream) {
    const float* x     = (const float*)d_in[0];
    const int*   ei    = (const int*)d_in[1];
    const float* ea    = (const float*)d_in[2];
    const int*   batch = (const int*)d_in[3];
    const float* c1W   = (const float*)d_in[4];
    const float* c1b   = (const float*)d_in[5];
    const float* c1g   = (const float*)d_in[6];
    const float* c1be  = (const float*)d_in[7];
    const float* c1eW  = (const float*)d_in[8];
    const float* c1eb  = (const float*)d_in[9];
    const float* cW    = (const float*)d_in[10];
    const float* cb    = (const float*)d_in[11];
    const float* cg    = (const float*)d_in[12];
    const float* cbe   = (const float*)d_in[13];
    const float* ceW   = (const float*)d_in[14];
    const float* ceb   = (const float*)d_in[15];
    const float* cls1W = (const float*)d_in[16];
    const float* cls1b = (const float*)d_in[17];
    const float* clsW  = (const float*)d_in[18];
    const float* clsb  = (const float*)d_in[19];
    const float* fW    = (const float*)d_in[20];
    const float* fb    = (const float*)d_in[21];
    float* out = (float*)d_out;

    char* ws = (char*)d_ws;
    size_t off = 0;
    auto alloc = [&](size_t bytes) {
        void* p = ws + off;
        off += (bytes + 255) & ~(size_t)255;
        return p;
    };
    const int NBLK = (N_NODES + 1023) / 1024;  // 49
    int*   srcs   = (int*)alloc((size_t)N_EDGES * 4);
    int*   dsts   = (int*)alloc((size_t)N_EDGES * 4);
    int*   cursor = (int*)alloc((size_t)N_NODES * 4);
    int*   cnt    = (int*)alloc((size_t)N_NODES * 4);
    int*   incl   = (int*)alloc((size_t)NBLK * 1024 * 4);
    int*   bsum   = (int*)alloc((size_t)NBLK * 4);
    int*   bex    = (int*)alloc((size_t)NBLK * 4);
    __hip_bfloat16* eas = (__hip_bfloat16*)alloc((size_t)N_EDGES * 16 * 2);  // 25.6 MB
    float* t32    = (float*)alloc((size_t)N_NODES * 128 * 4);                // 25.6 MB
    __hip_bfloat16* h1     = (__hip_bfloat16*)alloc((size_t)N_NODES * 128 * 2);
    float*          pool   = (float*)alloc((size_t)N_MOLS * 128 * 4);
    __hip_bfloat16* concat = (__hip_bfloat16*)alloc((size_t)N_NODES * 640 * 2); // 64 MB
    __hip_bfloat16* clsA   = (__hip_bfloat16*)alloc((size_t)N_NODES * 256 * 2);
    __hip_bfloat16* wt1    = (__hip_bfloat16*)alloc((size_t)128 * 64 * 2);
    __hip_bfloat16* wtc    = (__hip_bfloat16*)alloc((size_t)4 * 128 * 128 * 2);
    __hip_bfloat16* wtcls1 = (__hip_bfloat16*)alloc((size_t)256 * 640 * 2);
    __hip_bfloat16* wtcls  = (__hip_bfloat16*)alloc((size_t)2 * 256 * 256 * 2);
    __hip_bfloat16* ewt1   = (__hip_bfloat16*)alloc((size_t)64 * 16 * 2);
    __hip_bfloat16* ewtc   = (__hip_bfloat16*)alloc((size_t)4 * 128 * 16 * 2);
    __hip_bfloat16* clsB   = concat;  // overlay: concat dead after cls1

    hipMemsetAsync(cnt, 0, (size_t)N_NODES * 4, stream);
    hipMemsetAsync(pool, 0, (size_t)N_MOLS * 128 * 4, stream);

    // ---- edge sort by dst (emits srcs/dsts/eas-bf16) ----
    hist_kernel<<<(N_EDGES + 255) / 256, 256, 0, stream>>>(ei, cnt);
    scan1_kernel<<<NBLK, 1024, 0, stream>>>(cnt, incl, bsum);
    scan2_kernel<<<1, 64, 0, stream>>>(bsum, bex, NBLK);
    scan3_kernel<<<NBLK, 1024, 0, stream>>>(cnt, incl, bex, cursor);
    scatter_kernel<<<(N_EDGES + 255) / 256, 256, 0, stream>>>(ei, cursor, ea, srcs, dsts, eas);

    // ---- all weight converts in one launch ----
    cvt_all_kernel<<<(377856 + 255) / 256, 256, 0, stream>>>(
        c1W, cW, cls1W, clsW, c1eW, ceW, wt1, wtc, wtcls1, wtcls, ewt1, ewtc);

    const int NEB = N_EDGES / EPB;             // 6250
    const int GR = (N_NODES + 63) / 64;        // 782 row tiles

    // ---- conv1: x [N,64] f32 -> h1 [N,128] ----
    hipMemsetAsync(t32, 0, (size_t)N_NODES * 64 * 4, stream);
    edge_mfma_kernel<64, true><<<NEB, 256, 0, stream>>>(
        x, 64, eas, srcs, dsts, ewt1, c1eb, t32);
    mfma_lin_kernel<64, 128, ACT_BN_DL, 1><<<dim3(GR, 2), 256, 0, stream>>>(
        x, 64, t32, wt1, c1b, c1g, c1be, h1, 128);

    // ---- conv layers 0..3 -> concat slices ----
    for (int i = 0; i < 4; ++i) {
        const void* hin = (i == 0) ? (const void*)h1 : (const void*)(concat + (size_t)(i - 1) * 128);
        int ld = (i == 0) ? 128 : 640;
        hipMemsetAsync(t32, 0, (size_t)N_NODES * 128 * 4, stream);
        edge_mfma_kernel<128, false><<<NEB, 256, 0, stream>>>(
            hin, ld, eas, srcs, dsts, ewtc + (size_t)i * 2048, ceb + (size_t)i * 128, t32);
        mfma_lin_kernel<128, 128, ACT_BN_DL, 2><<<dim3(GR, 2), 256, 0, stream>>>(
            hin, ld, t32, wtc + (size_t)i * 16384, cb + i * 128,
            cg + i * 128, cbe + i * 128, concat + (size_t)i * 128, 640);
    }

    // ---- global add pool (cols 384..511) -> cols 512..639 ----
    pool_add_kernel<<<(N_NODES * 128 + 255) / 256, 256, 0, stream>>>(concat, batch, pool);
    pool_gather_kernel<<<(N_NODES * 128 + 255) / 256, 256, 0, stream>>>(concat, batch, pool);

    // ---- classifier ----
    mfma_lin_kernel<640, 256, ACT_NONE, 0><<<dim3(GR, 4), 256, 0, stream>>>(
        concat, 640, nullptr, wtcls1, cls1b, nullptr, nullptr, clsA, 256);
    mfma_lin_kernel<256, 256, ACT_LEAKY, 0><<<dim3(GR, 4), 256, 0, stream>>>(
        clsA, 256, nullptr, wtcls, clsb, nullptr, nullptr, clsB, 256);
    mfma_lin_kernel<256, 256, ACT_LEAKY, 0><<<dim3(GR, 4), 256, 0, stream>>>(
        clsB, 256, nullptr, wtcls + 256 * 256, clsb + 256, nullptr, nullptr, clsA, 256);
    final_kernel<<<N_NODES / 4, 256, 0, stream>>>(clsA, fW, fb, out);
}